// Round 1
// 529.345 us; speedup vs baseline: 1.0789x; 1.0789x over previous
//
#include <hip/hip_runtime.h>
#include <stdint.h>

#define B_ 32
#define S_ 2048
#define D_ 1024

typedef __attribute__((ext_vector_type(16))) float f32x16;

__device__ __forceinline__ void async_copy16(const void* g, void* l) {
  __builtin_amdgcn_global_load_lds(
      (const __attribute__((address_space(1))) uint32_t*)g,
      (__attribute__((address_space(3))) uint32_t*)l, 16, 0, 0);
}

// image row layout: per (b,dt) image = 16 slabs x (128 m-rows x 128 bytes).
// Row m, slab-local k in [0,128): 8 chunks of 16B. Chunk ch=(g<<1)|bh holds
// fp8 of local k = g*32+bh*8+{0..7} (bytes 0-7) and g*32+16+bh*8+{0..7}
// (bytes 8-15), stored at position (ch ^ (m&7))*16  [XOR swizzle: makes the
// gram's stride-128B b128 frag reads conflict-free across 32 lanes].
__device__ __forceinline__ int row_off(int m, int ch) {
  return m * 128 + ((ch ^ (m & 7)) << 4);
}

// ---------------- prepass: transpose + fp8 cast + fused column stats ----------------
// COPY=true additionally writes out = x (identity copy), removing the need for a
// full apply pass later (zerocol only touches killed columns).
template <bool COPY>
__global__ __launch_bounds__(256) void prepass_kernel(const float* __restrict__ x,
                                                      uint8_t* __restrict__ xt,
                                                      float2* __restrict__ part,
                                                      float* __restrict__ out) {
  __shared__ float s_s[256 * 4];
  __shared__ float s_q[256 * 4];
  int dt = blockIdx.x;    // 0..7
  int slab = blockIdx.y;  // 0..15
  int b = blockIdx.z;     // 0..31
  int t = threadIdx.x;
  int q = t & 31;   // m-quad: columns 4q..4q+3
  int e = t >> 5;   // eighth: g = e>>1, bh = e&1
  int g = e >> 1, bh = e & 1;

  const size_t base = ((size_t)b * S_ + (size_t)slab * 128 + g * 32 + bh * 8) * D_ +
                      dt * 128 + q * 4;
  const float* xb = x + base;
  float4 r[16];
#pragma unroll
  for (int j = 0; j < 8; ++j) r[j] = *(const float4*)(xb + (size_t)j * D_);
#pragma unroll
  for (int j = 0; j < 8; ++j) r[8 + j] = *(const float4*)(xb + (size_t)(16 + j) * D_);

  if (COPY) {
    float* ob = out + base;
#pragma unroll
    for (int j = 0; j < 8; ++j) *(float4*)(ob + (size_t)j * D_) = r[j];
#pragma unroll
    for (int j = 0; j < 8; ++j) *(float4*)(ob + (size_t)(16 + j) * D_) = r[8 + j];
  }

  uint8_t* img = xt + (((size_t)b * 8 + dt) * 16 + slab) * 16384;
#pragma unroll
  for (int c = 0; c < 4; ++c) {
    float v[16];
#pragma unroll
    for (int j = 0; j < 16; ++j) v[j] = ((const float*)&r[j])[c];
    float ps = 0.f, pq = 0.f;
#pragma unroll
    for (int j = 0; j < 16; ++j) { ps += v[j]; pq += v[j] * v[j]; }
    s_s[t * 4 + c] = ps;
    s_q[t * 4 + c] = pq;
    uint32_t w0 = 0, w1 = 0, w2 = 0, w3 = 0;
    w0 = __builtin_amdgcn_cvt_pk_fp8_f32(v[0], v[1], w0, false);
    w0 = __builtin_amdgcn_cvt_pk_fp8_f32(v[2], v[3], w0, true);
    w1 = __builtin_amdgcn_cvt_pk_fp8_f32(v[4], v[5], w1, false);
    w1 = __builtin_amdgcn_cvt_pk_fp8_f32(v[6], v[7], w1, true);
    w2 = __builtin_amdgcn_cvt_pk_fp8_f32(v[8], v[9], w2, false);
    w2 = __builtin_amdgcn_cvt_pk_fp8_f32(v[10], v[11], w2, true);
    w3 = __builtin_amdgcn_cvt_pk_fp8_f32(v[12], v[13], w3, false);
    w3 = __builtin_amdgcn_cvt_pk_fp8_f32(v[14], v[15], w3, true);
    int m = 4 * q + c;
    *(uint4*)(img + row_off(m, (g << 1) | bh)) = make_uint4(w0, w1, w2, w3);
  }
  __syncthreads();
  if (t < 128) {
    int m = t, qq = m >> 2, cc = m & 3;
    float ss = 0.f, sq = 0.f;
#pragma unroll
    for (int ee = 0; ee < 8; ++ee) {
      ss += s_s[(qq + 32 * ee) * 4 + cc];
      sq += s_q[(qq + 32 * ee) * 4 + cc];
    }
    part[(size_t)slab * 32768 + b * 1024 + dt * 128 + m] = make_float2(ss, sq);
  }
}

__global__ void finalize_kernel(const float2* __restrict__ part,
                                float* __restrict__ meanB,
                                float* __restrict__ stdB) {
  int i = blockIdx.x * 256 + threadIdx.x;  // 32768 = (b,d)
  float s = 0.f, qv = 0.f;
#pragma unroll
  for (int sl = 0; sl < 16; ++sl) {
    float2 p = part[(size_t)sl * 32768 + i];
    s += p.x;
    qv += p.y;
  }
  float m = s * (1.0f / (float)S_);
  float var = (qv - s * m) * (1.0f / (float)(S_ - 1));
  meanB[i] = m;
  stdB[i] = sqrtf(fmaxf(var, 0.f));
}

// ---------------- Gram (upper-triangle tiles, fp8 MFMA) + threshold + colkill ----------------
__global__ __launch_bounds__(256) void gram_kernel(const uint8_t* __restrict__ xt,
                                                   const float* __restrict__ meanB,
                                                   const float* __restrict__ stdB,
                                                   int* __restrict__ colkill) {
  __shared__ uint8_t smA[16384];
  __shared__ uint8_t smB[16384];
  int b = blockIdx.y;
  int p = blockIdx.x;  // 0..35 -> (i,j), i<=j
  int i = 0;
  while (p >= 8 - i) { p -= 8 - i; ++i; }
  int j = i + p;

  int tid = threadIdx.x;
  int lane = tid & 63, wave = tid >> 6;
  int wm = wave & 1, wn = wave >> 1;
  int l31 = lane & 31, half = lane >> 5;

  f32x16 acc[2][2];
#pragma unroll
  for (int a = 0; a < 2; ++a)
#pragma unroll
    for (int c = 0; c < 2; ++c)
#pragma unroll
      for (int r = 0; r < 16; ++r) acc[a][c][r] = 0.f;

  const uint8_t* gA = xt + ((size_t)b * 8 + i) * 262144;
  const uint8_t* gB = xt + ((size_t)b * 8 + j) * 262144;
  bool diag = (i == j);

  for (int sl = 0; sl < 16; ++sl) {
    __syncthreads();
    const uint8_t* srcA = gA + (size_t)sl * 16384;
    for (int c = wave; c < 16; c += 4)
      async_copy16(srcA + c * 1024 + lane * 16, (void*)(smA + c * 1024));
    if (!diag) {
      const uint8_t* srcB = gB + (size_t)sl * 16384;
      for (int c = wave; c < 16; c += 4)
        async_copy16(srcB + c * 1024 + lane * 16, (void*)(smB + c * 1024));
    }
    __syncthreads();

    const uint8_t* bA = smA;
    const uint8_t* bB = diag ? smA : smB;
#pragma unroll
    for (int g = 0; g < 4; ++g) {
      ulonglong2 a0 = *(const ulonglong2*)(bA + row_off(wm * 64 + l31, (g << 1) | half));
      ulonglong2 a1 = *(const ulonglong2*)(bA + row_off(wm * 64 + 32 + l31, (g << 1) | half));
      ulonglong2 b0 = *(const ulonglong2*)(bB + row_off(wn * 64 + l31, (g << 1) | half));
      ulonglong2 b1 = *(const ulonglong2*)(bB + row_off(wn * 64 + 32 + l31, (g << 1) | half));
      acc[0][0] = __builtin_amdgcn_mfma_f32_32x32x16_fp8_fp8((long)a0.x, (long)b0.x, acc[0][0], 0, 0, 0);
      acc[0][1] = __builtin_amdgcn_mfma_f32_32x32x16_fp8_fp8((long)a0.x, (long)b1.x, acc[0][1], 0, 0, 0);
      acc[1][0] = __builtin_amdgcn_mfma_f32_32x32x16_fp8_fp8((long)a1.x, (long)b0.x, acc[1][0], 0, 0, 0);
      acc[1][1] = __builtin_amdgcn_mfma_f32_32x32x16_fp8_fp8((long)a1.x, (long)b1.x, acc[1][1], 0, 0, 0);
      acc[0][0] = __builtin_amdgcn_mfma_f32_32x32x16_fp8_fp8((long)a0.y, (long)b0.y, acc[0][0], 0, 0, 0);
      acc[0][1] = __builtin_amdgcn_mfma_f32_32x32x16_fp8_fp8((long)a0.y, (long)b1.y, acc[0][1], 0, 0, 0);
      acc[1][0] = __builtin_amdgcn_mfma_f32_32x32x16_fp8_fp8((long)a1.y, (long)b0.y, acc[1][0], 0, 0, 0);
      acc[1][1] = __builtin_amdgcn_mfma_f32_32x32x16_fp8_fp8((long)a1.y, (long)b1.y, acc[1][1], 0, 0, 0);
    }
  }

  // epilogue: cov from raw Gram, threshold vs 0.5*std_d*std_e, kill both cols
  const float* mb = meanB + b * D_;
  const float* sb = stdB + b * D_;
#pragma unroll
  for (int t = 0; t < 2; ++t) {
#pragma unroll
    for (int u = 0; u < 2; ++u) {
      int e = j * 128 + wn * 64 + u * 32 + l31;
      float me = mb[e], se05 = 0.5f * sb[e];
#pragma unroll
      for (int r = 0; r < 16; ++r) {
        int row = half * 4 + (r & 3) + 8 * (r >> 2);
        int d = i * 128 + wm * 64 + t * 32 + row;
        float cov = (acc[t][u][r] - (float)S_ * mb[d] * me) * (1.0f / (float)(S_ - 1));
        if (d != e && fabsf(cov) > se05 * sb[d]) {
          atomicOr(colkill + b * D_ + e, 1);
          atomicOr(colkill + b * D_ + d, 1);
        }
      }
    }
  }
}

// ---------------- fallback: full apply pass (old path, ws too small) ----------------
__global__ void apply_kernel(const float* __restrict__ x,
                             const int* __restrict__ colkill,
                             float* __restrict__ out) {
  size_t idx = (size_t)blockIdx.x * 256 + threadIdx.x;  // float4 index
  const float4 v = ((const float4*)x)[idx];
  size_t e0 = idx * 4;
  int d = (int)(e0 & (D_ - 1));
  int b = (int)(e0 >> 21);  // S_*D_ = 2^21
  const int4 k = *(const int4*)(colkill + b * D_ + d);
  float4 o;
  o.x = k.x ? 0.f : v.x;
  o.y = k.y ? 0.f : v.y;
  o.z = k.z ? 0.f : v.z;
  o.w = k.w ? 0.f : v.w;
  ((float4*)out)[idx] = o;
}

// ---------------- new path: zero only the killed columns of out (= x copy) ----------------
__global__ __launch_bounds__(256) void zerocol_kernel(const int* __restrict__ colkill,
                                                      float* __restrict__ out) {
  int bd = blockIdx.x * 256 + threadIdx.x;  // (b,d) in [0, 32768)
  if (colkill[bd] == 0) return;
  int b = bd >> 10, d = bd & (D_ - 1);
  float* p = out + (size_t)b * S_ * D_ + d;
#pragma unroll 8
  for (int s = 0; s < S_; ++s) p[(size_t)s * D_] = 0.f;
}

extern "C" void kernel_launch(void* const* d_in, const int* in_sizes, int n_in,
                              void* d_out, int out_size, void* d_ws, size_t ws_size,
                              hipStream_t stream) {
  const float* x = (const float*)d_in[0];
  float* out = (float*)d_out;

  // Preferred layout (needs ws >= 69 MiB):
  //   ws: xt fp8 images 64 MiB | part 4 MiB | meanB/stdB/colkill 128 KiB each.
  // prepass fuses out=x copy; apply pass replaced by zerocol (touches only
  // killed columns -> ~0 traffic on typical inputs). Saves one full 256 MiB
  // read of x vs the fallback structure.
  const size_t need = ((size_t)69 << 20);
  if (ws_size >= need) {
    uint8_t* xt = (uint8_t*)d_ws;
    float2* part = (float2*)((uint8_t*)d_ws + ((size_t)64 << 20));
    float* meanB = (float*)((uint8_t*)d_ws + ((size_t)68 << 20));
    float* stdB = meanB + 32768;
    int* colkill = (int*)(stdB + 32768);

    hipMemsetAsync(colkill, 0, 32768 * sizeof(int), stream);
    prepass_kernel<true><<<dim3(8, 16, 32), 256, 0, stream>>>(x, xt, part, out);
    finalize_kernel<<<128, 256, 0, stream>>>(part, meanB, stdB);
    gram_kernel<<<dim3(36, 32), 256, 0, stream>>>(xt, meanB, stdB, colkill);
    zerocol_kernel<<<128, 256, 0, stream>>>(colkill, out);
  } else {
    // Fallback: fp8 images live in d_out (64 MiB < 256 MiB); apply_kernel
    // fully overwrites d_out afterwards.
    uint8_t* xt = (uint8_t*)d_out;
    float2* part = (float2*)d_ws;
    float* meanB = (float*)((uint8_t*)d_ws + (16 * 32768) * sizeof(float2));
    float* stdB = meanB + 32768;
    int* colkill = (int*)(stdB + 32768);

    hipMemsetAsync(colkill, 0, 32768 * sizeof(int), stream);
    prepass_kernel<false><<<dim3(8, 16, 32), 256, 0, stream>>>(x, xt, part, nullptr);
    finalize_kernel<<<128, 256, 0, stream>>>(part, meanB, stdB);
    gram_kernel<<<dim3(36, 32), 256, 0, stream>>>(xt, meanB, stdB, colkill);
    apply_kernel<<<65536, 256, 0, stream>>>(x, colkill, out);
  }
}

// Round 2
// 520.116 us; speedup vs baseline: 1.0981x; 1.0177x over previous
//
#include <hip/hip_runtime.h>
#include <stdint.h>

#define B_ 32
#define S_ 2048
#define D_ 1024

typedef __attribute__((ext_vector_type(16))) float f32x16;
typedef __attribute__((ext_vector_type(4))) float f32x4;

__device__ __forceinline__ void async_copy16(const void* g, void* l) {
  __builtin_amdgcn_global_load_lds(
      (const __attribute__((address_space(1))) uint32_t*)g,
      (__attribute__((address_space(3))) uint32_t*)l, 16, 0, 0);
}

// image row layout: per (b,dt) image = 16 slabs x (128 m-rows x 128 bytes).
// Row m, slab-local k in [0,128): 8 chunks of 16B. Chunk ch=(g<<1)|bh holds
// fp8 of local k = g*32+bh*8+{0..7} (bytes 0-7) and g*32+16+bh*8+{0..7}
// (bytes 8-15), stored at position (ch ^ (m&7))*16  [XOR swizzle: makes the
// gram's stride-128B b128 frag reads conflict-free across 32 lanes].
__device__ __forceinline__ int row_off(int m, int ch) {
  return m * 128 + ((ch ^ (m & 7)) << 4);
}

// ---------------- prepass: transpose + fp8 cast + fused column stats ----------------
// COPY=true additionally writes out = x (identity copy); zerocol later touches
// only killed columns. Non-temporal on x/out (read-once / write-once streams)
// keeps L2/L3 free for xt, which gram re-reads 9x.
template <bool COPY>
__global__ __launch_bounds__(256) void prepass_kernel(const float* __restrict__ x,
                                                      uint8_t* __restrict__ xt,
                                                      float2* __restrict__ part,
                                                      float* __restrict__ out) {
  __shared__ float s_s[256 * 4];
  __shared__ float s_q[256 * 4];
  int dt = blockIdx.x;    // 0..7
  int slab = blockIdx.y;  // 0..15
  int b = blockIdx.z;     // 0..31
  int t = threadIdx.x;
  int q = t & 31;   // m-quad: columns 4q..4q+3
  int e = t >> 5;   // eighth: g = e>>1, bh = e&1
  int g = e >> 1, bh = e & 1;

  const size_t base = ((size_t)b * S_ + (size_t)slab * 128 + g * 32 + bh * 8) * D_ +
                      dt * 128 + q * 4;
  const f32x4* xb = (const f32x4*)(x + base);
  f32x4 r[16];
#pragma unroll
  for (int j = 0; j < 8; ++j) r[j] = __builtin_nontemporal_load(xb + (size_t)j * (D_ / 4));
#pragma unroll
  for (int j = 0; j < 8; ++j)
    r[8 + j] = __builtin_nontemporal_load(xb + (size_t)(16 + j) * (D_ / 4));

  if (COPY) {
    f32x4* ob = (f32x4*)(out + base);
#pragma unroll
    for (int j = 0; j < 8; ++j) __builtin_nontemporal_store(r[j], ob + (size_t)j * (D_ / 4));
#pragma unroll
    for (int j = 0; j < 8; ++j)
      __builtin_nontemporal_store(r[8 + j], ob + (size_t)(16 + j) * (D_ / 4));
  }

  uint8_t* img = xt + (((size_t)b * 8 + dt) * 16 + slab) * 16384;
#pragma unroll
  for (int c = 0; c < 4; ++c) {
    float v[16];
#pragma unroll
    for (int j = 0; j < 16; ++j) v[j] = r[j][c];
    float ps = 0.f, pq = 0.f;
#pragma unroll
    for (int j = 0; j < 16; ++j) { ps += v[j]; pq += v[j] * v[j]; }
    s_s[t * 4 + c] = ps;
    s_q[t * 4 + c] = pq;
    uint32_t w0 = 0, w1 = 0, w2 = 0, w3 = 0;
    w0 = __builtin_amdgcn_cvt_pk_fp8_f32(v[0], v[1], w0, false);
    w0 = __builtin_amdgcn_cvt_pk_fp8_f32(v[2], v[3], w0, true);
    w1 = __builtin_amdgcn_cvt_pk_fp8_f32(v[4], v[5], w1, false);
    w1 = __builtin_amdgcn_cvt_pk_fp8_f32(v[6], v[7], w1, true);
    w2 = __builtin_amdgcn_cvt_pk_fp8_f32(v[8], v[9], w2, false);
    w2 = __builtin_amdgcn_cvt_pk_fp8_f32(v[10], v[11], w2, true);
    w3 = __builtin_amdgcn_cvt_pk_fp8_f32(v[12], v[13], w3, false);
    w3 = __builtin_amdgcn_cvt_pk_fp8_f32(v[14], v[15], w3, true);
    int m = 4 * q + c;
    *(uint4*)(img + row_off(m, (g << 1) | bh)) = make_uint4(w0, w1, w2, w3);
  }
  __syncthreads();
  if (t < 128) {
    int m = t, qq = m >> 2, cc = m & 3;
    float ss = 0.f, sq = 0.f;
#pragma unroll
    for (int ee = 0; ee < 8; ++ee) {
      ss += s_s[(qq + 32 * ee) * 4 + cc];
      sq += s_q[(qq + 32 * ee) * 4 + cc];
    }
    part[(size_t)slab * 32768 + b * 1024 + dt * 128 + m] = make_float2(ss, sq);
  }
}

// ---------------- Gram (upper-triangle tiles, fp8 MFMA, double-buffered) ----------------
// Fuses the old finalize pass: per-block strip stats are reduced from `part`
// inline (L2-resident), overlapped with the prologue staging latency.
// Staging is double-buffered: slab sl+1 is issued into buf^1 BEFORE computing
// slab sl, so the forced vmcnt(0)+barrier drain lands after the MFMA cluster
// instead of exposing full L2/L3 latency every slab (T3 minimum-2-phase).
__global__ __launch_bounds__(256) void gram_kernel(const uint8_t* __restrict__ xt,
                                                   const float2* __restrict__ part,
                                                   int* __restrict__ colkill) {
  __shared__ uint8_t smA[2][16384];
  __shared__ uint8_t smB[2][16384];
  __shared__ float s_mean[256];
  __shared__ float s_std[256];
  int b = blockIdx.y;
  int p = blockIdx.x;  // 0..35 -> (i,j), i<=j
  int i = 0;
  while (p >= 8 - i) { p -= 8 - i; ++i; }
  int j = i + p;

  int tid = threadIdx.x;
  int lane = tid & 63, wave = tid >> 6;
  int wm = wave & 1, wn = wave >> 1;
  int l31 = lane & 31, half = lane >> 5;
  bool diag = (i == j);

  const uint8_t* gA = xt + ((size_t)b * 8 + i) * 262144;
  const uint8_t* gB = xt + ((size_t)b * 8 + j) * 262144;

  // prologue: stage slab 0 into buf 0
  for (int c = wave; c < 16; c += 4)
    async_copy16(gA + c * 1024 + lane * 16, (void*)(smA[0] + c * 1024));
  if (!diag) {
    for (int c = wave; c < 16; c += 4)
      async_copy16(gB + c * 1024 + lane * 16, (void*)(smB[0] + c * 1024));
  }

  // inline strip stats (overlaps staging latency). tid<128 -> strip i, else j.
  {
    int dl = tid & 127;
    int strip = (tid >> 7) ? j : i;
    int d = strip * 128 + dl;
    float s = 0.f, qv = 0.f;
#pragma unroll
    for (int sl = 0; sl < 16; ++sl) {
      float2 pp = part[(size_t)sl * 32768 + b * 1024 + d];
      s += pp.x;
      qv += pp.y;
    }
    float m = s * (1.0f / (float)S_);
    float var = (qv - s * m) * (1.0f / (float)(S_ - 1));
    s_mean[tid] = m;
    s_std[tid] = sqrtf(fmaxf(var, 0.f));
  }

  f32x16 acc[2][2];
#pragma unroll
  for (int a = 0; a < 2; ++a)
#pragma unroll
    for (int c = 0; c < 2; ++c)
#pragma unroll
      for (int r = 0; r < 16; ++r) acc[a][c][r] = 0.f;

  __syncthreads();  // compiler drains vmcnt(0): slab 0 staged, stats visible

  for (int sl = 0; sl < 16; ++sl) {
    int cur = sl & 1;
    if (sl < 15) {  // issue next slab into the other buffer BEFORE compute
      const uint8_t* srcA = gA + (size_t)(sl + 1) * 16384;
      for (int c = wave; c < 16; c += 4)
        async_copy16(srcA + c * 1024 + lane * 16, (void*)(smA[cur ^ 1] + c * 1024));
      if (!diag) {
        const uint8_t* srcB = gB + (size_t)(sl + 1) * 16384;
        for (int c = wave; c < 16; c += 4)
          async_copy16(srcB + c * 1024 + lane * 16, (void*)(smB[cur ^ 1] + c * 1024));
      }
    }
    __builtin_amdgcn_sched_barrier(0);  // pin stage-issue before the MFMA cluster

    const uint8_t* bA = smA[cur];
    const uint8_t* bB = diag ? smA[cur] : smB[cur];
#pragma unroll
    for (int g = 0; g < 4; ++g) {
      ulonglong2 a0 = *(const ulonglong2*)(bA + row_off(wm * 64 + l31, (g << 1) | half));
      ulonglong2 a1 = *(const ulonglong2*)(bA + row_off(wm * 64 + 32 + l31, (g << 1) | half));
      ulonglong2 b0 = *(const ulonglong2*)(bB + row_off(wn * 64 + l31, (g << 1) | half));
      ulonglong2 b1 = *(const ulonglong2*)(bB + row_off(wn * 64 + 32 + l31, (g << 1) | half));
      acc[0][0] = __builtin_amdgcn_mfma_f32_32x32x16_fp8_fp8((long)a0.x, (long)b0.x, acc[0][0], 0, 0, 0);
      acc[0][1] = __builtin_amdgcn_mfma_f32_32x32x16_fp8_fp8((long)a0.x, (long)b1.x, acc[0][1], 0, 0, 0);
      acc[1][0] = __builtin_amdgcn_mfma_f32_32x32x16_fp8_fp8((long)a1.x, (long)b0.x, acc[1][0], 0, 0, 0);
      acc[1][1] = __builtin_amdgcn_mfma_f32_32x32x16_fp8_fp8((long)a1.x, (long)b1.x, acc[1][1], 0, 0, 0);
      acc[0][0] = __builtin_amdgcn_mfma_f32_32x32x16_fp8_fp8((long)a0.y, (long)b0.y, acc[0][0], 0, 0, 0);
      acc[0][1] = __builtin_amdgcn_mfma_f32_32x32x16_fp8_fp8((long)a0.y, (long)b1.y, acc[0][1], 0, 0, 0);
      acc[1][0] = __builtin_amdgcn_mfma_f32_32x32x16_fp8_fp8((long)a1.y, (long)b0.y, acc[1][0], 0, 0, 0);
      acc[1][1] = __builtin_amdgcn_mfma_f32_32x32x16_fp8_fp8((long)a1.y, (long)b1.y, acc[1][1], 0, 0, 0);
    }
    __syncthreads();  // drains vmcnt(0) for slab sl+1; protects buf cur reuse
  }

  // epilogue: cov from raw Gram, threshold vs 0.5*std_d*std_e, kill both cols
  const float* mbI = s_mean;
  const float* sbI = s_std;
  const float* mbJ = s_mean + 128;
  const float* sbJ = s_std + 128;
#pragma unroll
  for (int t = 0; t < 2; ++t) {
#pragma unroll
    for (int u = 0; u < 2; ++u) {
      int el = wn * 64 + u * 32 + l31;
      int ee = j * 128 + el;
      float me = mbJ[el], se05 = 0.5f * sbJ[el];
#pragma unroll
      for (int r = 0; r < 16; ++r) {
        int row = half * 4 + (r & 3) + 8 * (r >> 2);
        int dl = wm * 64 + t * 32 + row;
        int d = i * 128 + dl;
        float cov = (acc[t][u][r] - (float)S_ * mbI[dl] * me) * (1.0f / (float)(S_ - 1));
        if (d != ee && fabsf(cov) > se05 * sbI[dl]) {
          atomicOr(colkill + b * D_ + ee, 1);
          atomicOr(colkill + b * D_ + d, 1);
        }
      }
    }
  }
}

// ---------------- fallback: full apply pass (old path, ws too small) ----------------
__global__ void apply_kernel(const float* __restrict__ x,
                             const int* __restrict__ colkill,
                             float* __restrict__ out) {
  size_t idx = (size_t)blockIdx.x * 256 + threadIdx.x;  // float4 index
  const float4 v = ((const float4*)x)[idx];
  size_t e0 = idx * 4;
  int d = (int)(e0 & (D_ - 1));
  int b = (int)(e0 >> 21);  // S_*D_ = 2^21
  const int4 k = *(const int4*)(colkill + b * D_ + d);
  float4 o;
  o.x = k.x ? 0.f : v.x;
  o.y = k.y ? 0.f : v.y;
  o.z = k.z ? 0.f : v.z;
  o.w = k.w ? 0.f : v.w;
  ((float4*)out)[idx] = o;
}

// ---------------- zero only the killed columns of out (= x copy) ----------------
__global__ __launch_bounds__(256) void zerocol_kernel(const int* __restrict__ colkill,
                                                      float* __restrict__ out) {
  int bd = blockIdx.x * 256 + threadIdx.x;  // (b,d) in [0, 32768)
  if (colkill[bd] == 0) return;
  int b = bd >> 10, d = bd & (D_ - 1);
  float* p = out + (size_t)b * S_ * D_ + d;
#pragma unroll 8
  for (int s = 0; s < S_; ++s) p[(size_t)s * D_] = 0.f;
}

extern "C" void kernel_launch(void* const* d_in, const int* in_sizes, int n_in,
                              void* d_out, int out_size, void* d_ws, size_t ws_size,
                              hipStream_t stream) {
  const float* x = (const float*)d_in[0];
  float* out = (float*)d_out;

  // Preferred layout (needs ws >= 69 MiB):
  //   ws: xt fp8 images 64 MiB | part 4 MiB | colkill 128 KiB.
  // prepass fuses out=x copy; gram fuses the stats finalize; zerocol touches
  // only killed columns. x is read exactly once from HBM.
  const size_t need = ((size_t)69 << 20);
  if (ws_size >= need) {
    uint8_t* xt = (uint8_t*)d_ws;
    float2* part = (float2*)((uint8_t*)d_ws + ((size_t)64 << 20));
    int* colkill = (int*)((uint8_t*)d_ws + ((size_t)68 << 20));

    hipMemsetAsync(colkill, 0, 32768 * sizeof(int), stream);
    prepass_kernel<true><<<dim3(8, 16, 32), 256, 0, stream>>>(x, xt, part, out);
    gram_kernel<<<dim3(36, 32), 256, 0, stream>>>(xt, part, colkill);
    zerocol_kernel<<<128, 256, 0, stream>>>(colkill, out);
  } else {
    // Fallback: fp8 images live in d_out (64 MiB < 256 MiB); apply_kernel
    // fully overwrites d_out afterwards. Needs only ~4.2 MiB of ws.
    uint8_t* xt = (uint8_t*)d_out;
    float2* part = (float2*)d_ws;
    int* colkill = (int*)((uint8_t*)d_ws + (16 * 32768) * sizeof(float2));

    hipMemsetAsync(colkill, 0, 32768 * sizeof(int), stream);
    prepass_kernel<false><<<dim3(8, 16, 32), 256, 0, stream>>>(x, xt, part, nullptr);
    gram_kernel<<<dim3(36, 32), 256, 0, stream>>>(xt, part, colkill);
    apply_kernel<<<65536, 256, 0, stream>>>(x, colkill, out);
  }
}

// Round 3
// 510.438 us; speedup vs baseline: 1.1189x; 1.0190x over previous
//
#include <hip/hip_runtime.h>
#include <stdint.h>

#define B_ 32
#define S_ 2048
#define D_ 1024

typedef __attribute__((ext_vector_type(16))) float f32x16;
typedef __attribute__((ext_vector_type(4))) float f32x4;

__device__ __forceinline__ void async_copy16(const void* g, void* l) {
  __builtin_amdgcn_global_load_lds(
      (const __attribute__((address_space(1))) uint32_t*)g,
      (__attribute__((address_space(3))) uint32_t*)l, 16, 0, 0);
}

// image row layout: per (b,dt) image = 16 slabs x (128 m-rows x 128 bytes).
// Row m, slab-local k in [0,128): 8 chunks of 16B. Chunk ch=(g<<1)|bh holds
// fp8 of local k = g*32+bh*8+{0..7} (bytes 0-7) and g*32+16+bh*8+{0..7}
// (bytes 8-15), stored at position (ch ^ (m&7))*16  [XOR swizzle: makes the
// gram's stride-128B b128 frag reads conflict-free across 32 lanes].
__device__ __forceinline__ int row_off(int m, int ch) {
  return m * 128 + ((ch ^ (m & 7)) << 4);
}

// ---------------- prepass: transpose + fp8 cast + fused column stats ----------------
// COPY=true additionally writes out = x (identity copy); zerocol later touches
// only killed columns. Non-temporal on x/out (read-once / write-once streams)
// keeps L2/L3 free for xt, which gram re-reads ~8x. slab==0 blocks also zero
// their colkill slice (replaces the hipMemsetAsync dispatch).
template <bool COPY>
__global__ __launch_bounds__(256) void prepass_kernel(const float* __restrict__ x,
                                                      uint8_t* __restrict__ xt,
                                                      float2* __restrict__ part,
                                                      float* __restrict__ out,
                                                      int* __restrict__ colkill) {
  __shared__ float s_s[256 * 4];
  __shared__ float s_q[256 * 4];
  int dt = blockIdx.x;    // 0..7
  int slab = blockIdx.y;  // 0..15
  int b = blockIdx.z;     // 0..31
  int t = threadIdx.x;
  int q = t & 31;   // m-quad: columns 4q..4q+3
  int e = t >> 5;   // eighth: g = e>>1, bh = e&1
  int g = e >> 1, bh = e & 1;

  if (slab == 0 && t < 128) colkill[b * D_ + dt * 128 + t] = 0;

  const size_t base = ((size_t)b * S_ + (size_t)slab * 128 + g * 32 + bh * 8) * D_ +
                      dt * 128 + q * 4;
  const f32x4* xb = (const f32x4*)(x + base);
  f32x4 r[16];
#pragma unroll
  for (int j = 0; j < 8; ++j) r[j] = __builtin_nontemporal_load(xb + (size_t)j * (D_ / 4));
#pragma unroll
  for (int j = 0; j < 8; ++j)
    r[8 + j] = __builtin_nontemporal_load(xb + (size_t)(16 + j) * (D_ / 4));

  if (COPY) {
    f32x4* ob = (f32x4*)(out + base);
#pragma unroll
    for (int j = 0; j < 8; ++j) __builtin_nontemporal_store(r[j], ob + (size_t)j * (D_ / 4));
#pragma unroll
    for (int j = 0; j < 8; ++j)
      __builtin_nontemporal_store(r[8 + j], ob + (size_t)(16 + j) * (D_ / 4));
  }

  uint8_t* img = xt + (((size_t)b * 8 + dt) * 16 + slab) * 16384;
#pragma unroll
  for (int c = 0; c < 4; ++c) {
    float v[16];
#pragma unroll
    for (int j = 0; j < 16; ++j) v[j] = r[j][c];
    float ps = 0.f, pq = 0.f;
#pragma unroll
    for (int j = 0; j < 16; ++j) { ps += v[j]; pq += v[j] * v[j]; }
    s_s[t * 4 + c] = ps;
    s_q[t * 4 + c] = pq;
    uint32_t w0 = 0, w1 = 0, w2 = 0, w3 = 0;
    w0 = __builtin_amdgcn_cvt_pk_fp8_f32(v[0], v[1], w0, false);
    w0 = __builtin_amdgcn_cvt_pk_fp8_f32(v[2], v[3], w0, true);
    w1 = __builtin_amdgcn_cvt_pk_fp8_f32(v[4], v[5], w1, false);
    w1 = __builtin_amdgcn_cvt_pk_fp8_f32(v[6], v[7], w1, true);
    w2 = __builtin_amdgcn_cvt_pk_fp8_f32(v[8], v[9], w2, false);
    w2 = __builtin_amdgcn_cvt_pk_fp8_f32(v[10], v[11], w2, true);
    w3 = __builtin_amdgcn_cvt_pk_fp8_f32(v[12], v[13], w3, false);
    w3 = __builtin_amdgcn_cvt_pk_fp8_f32(v[14], v[15], w3, true);
    int m = 4 * q + c;
    *(uint4*)(img + row_off(m, (g << 1) | bh)) = make_uint4(w0, w1, w2, w3);
  }
  __syncthreads();
  if (t < 128) {
    int m = t, qq = m >> 2, cc = m & 3;
    float ss = 0.f, sq = 0.f;
#pragma unroll
    for (int ee = 0; ee < 8; ++ee) {
      ss += s_s[(qq + 32 * ee) * 4 + cc];
      sq += s_q[(qq + 32 * ee) * 4 + cc];
    }
    part[(size_t)slab * 32768 + b * 1024 + dt * 128 + m] = make_float2(ss, sq);
  }
}

// ---------------- Gram (upper-triangle tiles, fp8 MFMA, double-buffered) ----------------
// XCD-clustered job map: hardware round-robins blockIdx.x across the 8 XCDs,
// so bid = xcd + 8*inner with xcd = b%8 puts ALL 36 tile-pairs of a batch on
// one XCD. A batch's 8 fp8 images = 2 MiB < 4 MiB per-XCD L2, so after one
// L3 fill per image the ~8x re-reads are XCD-local L2 hits instead of L3
// traffic (gram is staging-BW-bound: 512 MiB total staged vs 8 us of MFMA).
// Consecutive inner-jobs share strip i, further helping L2 reuse.
__global__ __launch_bounds__(256) void gram_kernel(const uint8_t* __restrict__ xt,
                                                   const float2* __restrict__ part,
                                                   int* __restrict__ colkill) {
  __shared__ uint8_t smA[2][16384];
  __shared__ uint8_t smB[2][16384];
  __shared__ float s_mean[256];
  __shared__ float s_std[256];
  int bid = blockIdx.x;      // 0..1151
  int xcd = bid & 7;
  int inner = bid >> 3;      // 0..143
  int p = inner % 36;        // tile-pair 0..35 -> (i,j), i<=j
  int b = (inner / 36) * 8 + xcd;  // batch, clustered per XCD
  int i = 0;
  while (p >= 8 - i) { p -= 8 - i; ++i; }
  int j = i + p;

  int tid = threadIdx.x;
  int lane = tid & 63, wave = tid >> 6;
  int wm = wave & 1, wn = wave >> 1;
  int l31 = lane & 31, half = lane >> 5;
  bool diag = (i == j);

  const uint8_t* gA = xt + ((size_t)b * 8 + i) * 262144;
  const uint8_t* gB = xt + ((size_t)b * 8 + j) * 262144;

  // prologue: stage slab 0 into buf 0
  for (int c = wave; c < 16; c += 4)
    async_copy16(gA + c * 1024 + lane * 16, (void*)(smA[0] + c * 1024));
  if (!diag) {
    for (int c = wave; c < 16; c += 4)
      async_copy16(gB + c * 1024 + lane * 16, (void*)(smB[0] + c * 1024));
  }

  // inline strip stats (overlaps staging latency). tid<128 -> strip i, else j.
  {
    int dl = tid & 127;
    int strip = (tid >> 7) ? j : i;
    int d = strip * 128 + dl;
    float s = 0.f, qv = 0.f;
#pragma unroll
    for (int sl = 0; sl < 16; ++sl) {
      float2 pp = part[(size_t)sl * 32768 + b * 1024 + d];
      s += pp.x;
      qv += pp.y;
    }
    float m = s * (1.0f / (float)S_);
    float var = (qv - s * m) * (1.0f / (float)(S_ - 1));
    s_mean[tid] = m;
    s_std[tid] = sqrtf(fmaxf(var, 0.f));
  }

  f32x16 acc[2][2];
#pragma unroll
  for (int a = 0; a < 2; ++a)
#pragma unroll
    for (int c = 0; c < 2; ++c)
#pragma unroll
      for (int r = 0; r < 16; ++r) acc[a][c][r] = 0.f;

  __syncthreads();  // compiler drains vmcnt(0): slab 0 staged, stats visible

  for (int sl = 0; sl < 16; ++sl) {
    int cur = sl & 1;
    if (sl < 15) {  // issue next slab into the other buffer BEFORE compute
      const uint8_t* srcA = gA + (size_t)(sl + 1) * 16384;
      for (int c = wave; c < 16; c += 4)
        async_copy16(srcA + c * 1024 + lane * 16, (void*)(smA[cur ^ 1] + c * 1024));
      if (!diag) {
        const uint8_t* srcB = gB + (size_t)(sl + 1) * 16384;
        for (int c = wave; c < 16; c += 4)
          async_copy16(srcB + c * 1024 + lane * 16, (void*)(smB[cur ^ 1] + c * 1024));
      }
    }
    __builtin_amdgcn_sched_barrier(0);  // pin stage-issue before the MFMA cluster

    const uint8_t* bA = smA[cur];
    const uint8_t* bB = diag ? smA[cur] : smB[cur];
#pragma unroll
    for (int g = 0; g < 4; ++g) {
      ulonglong2 a0 = *(const ulonglong2*)(bA + row_off(wm * 64 + l31, (g << 1) | half));
      ulonglong2 a1 = *(const ulonglong2*)(bA + row_off(wm * 64 + 32 + l31, (g << 1) | half));
      ulonglong2 b0 = *(const ulonglong2*)(bB + row_off(wn * 64 + l31, (g << 1) | half));
      ulonglong2 b1 = *(const ulonglong2*)(bB + row_off(wn * 64 + 32 + l31, (g << 1) | half));
      acc[0][0] = __builtin_amdgcn_mfma_f32_32x32x16_fp8_fp8((long)a0.x, (long)b0.x, acc[0][0], 0, 0, 0);
      acc[0][1] = __builtin_amdgcn_mfma_f32_32x32x16_fp8_fp8((long)a0.x, (long)b1.x, acc[0][1], 0, 0, 0);
      acc[1][0] = __builtin_amdgcn_mfma_f32_32x32x16_fp8_fp8((long)a1.x, (long)b0.x, acc[1][0], 0, 0, 0);
      acc[1][1] = __builtin_amdgcn_mfma_f32_32x32x16_fp8_fp8((long)a1.x, (long)b1.x, acc[1][1], 0, 0, 0);
      acc[0][0] = __builtin_amdgcn_mfma_f32_32x32x16_fp8_fp8((long)a0.y, (long)b0.y, acc[0][0], 0, 0, 0);
      acc[0][1] = __builtin_amdgcn_mfma_f32_32x32x16_fp8_fp8((long)a0.y, (long)b1.y, acc[0][1], 0, 0, 0);
      acc[1][0] = __builtin_amdgcn_mfma_f32_32x32x16_fp8_fp8((long)a1.y, (long)b0.y, acc[1][0], 0, 0, 0);
      acc[1][1] = __builtin_amdgcn_mfma_f32_32x32x16_fp8_fp8((long)a1.y, (long)b1.y, acc[1][1], 0, 0, 0);
    }
    __syncthreads();  // drains vmcnt(0) for slab sl+1; protects buf cur reuse
  }

  // epilogue: cov from raw Gram, threshold vs 0.5*std_d*std_e, kill both cols
  const float* mbI = s_mean;
  const float* sbI = s_std;
  const float* mbJ = s_mean + 128;
  const float* sbJ = s_std + 128;
#pragma unroll
  for (int t = 0; t < 2; ++t) {
#pragma unroll
    for (int u = 0; u < 2; ++u) {
      int el = wn * 64 + u * 32 + l31;
      int ee = j * 128 + el;
      float me = mbJ[el], se05 = 0.5f * sbJ[el];
#pragma unroll
      for (int r = 0; r < 16; ++r) {
        int row = half * 4 + (r & 3) + 8 * (r >> 2);
        int dl = wm * 64 + t * 32 + row;
        int d = i * 128 + dl;
        float cov = (acc[t][u][r] - (float)S_ * mbI[dl] * me) * (1.0f / (float)(S_ - 1));
        if (d != ee && fabsf(cov) > se05 * sbI[dl]) {
          atomicOr(colkill + b * D_ + ee, 1);
          atomicOr(colkill + b * D_ + d, 1);
        }
      }
    }
  }
}

// ---------------- fallback: full apply pass (old path, ws too small) ----------------
__global__ void apply_kernel(const float* __restrict__ x,
                             const int* __restrict__ colkill,
                             float* __restrict__ out) {
  size_t idx = (size_t)blockIdx.x * 256 + threadIdx.x;  // float4 index
  const float4 v = ((const float4*)x)[idx];
  size_t e0 = idx * 4;
  int d = (int)(e0 & (D_ - 1));
  int b = (int)(e0 >> 21);  // S_*D_ = 2^21
  const int4 k = *(const int4*)(colkill + b * D_ + d);
  float4 o;
  o.x = k.x ? 0.f : v.x;
  o.y = k.y ? 0.f : v.y;
  o.z = k.z ? 0.f : v.z;
  o.w = k.w ? 0.f : v.w;
  ((float4*)out)[idx] = o;
}

// ---------------- zero only the killed columns of out (= x copy) ----------------
__global__ __launch_bounds__(256) void zerocol_kernel(const int* __restrict__ colkill,
                                                      float* __restrict__ out) {
  int bd = blockIdx.x * 256 + threadIdx.x;  // (b,d) in [0, 32768)
  if (colkill[bd] == 0) return;
  int b = bd >> 10, d = bd & (D_ - 1);
  float* p = out + (size_t)b * S_ * D_ + d;
#pragma unroll 8
  for (int s = 0; s < S_; ++s) p[(size_t)s * D_] = 0.f;
}

extern "C" void kernel_launch(void* const* d_in, const int* in_sizes, int n_in,
                              void* d_out, int out_size, void* d_ws, size_t ws_size,
                              hipStream_t stream) {
  const float* x = (const float*)d_in[0];
  float* out = (float*)d_out;

  // Preferred layout (needs ws >= 69 MiB):
  //   ws: xt fp8 images 64 MiB | part 4 MiB | colkill 128 KiB.
  // prepass fuses out=x copy + colkill zeroing; gram fuses the stats finalize
  // and is XCD-clustered for L2 reuse; zerocol touches only killed columns.
  // x is read exactly once from HBM; 3 dispatches total.
  const size_t need = ((size_t)69 << 20);
  if (ws_size >= need) {
    uint8_t* xt = (uint8_t*)d_ws;
    float2* part = (float2*)((uint8_t*)d_ws + ((size_t)64 << 20));
    int* colkill = (int*)((uint8_t*)d_ws + ((size_t)68 << 20));

    prepass_kernel<true><<<dim3(8, 16, 32), 256, 0, stream>>>(x, xt, part, out, colkill);
    gram_kernel<<<dim3(1152), 256, 0, stream>>>(xt, part, colkill);
    zerocol_kernel<<<128, 256, 0, stream>>>(colkill, out);
  } else {
    // Fallback: fp8 images live in d_out (64 MiB < 256 MiB); apply_kernel
    // fully overwrites d_out afterwards. Needs only ~4.2 MiB of ws.
    uint8_t* xt = (uint8_t*)d_out;
    float2* part = (float2*)d_ws;
    int* colkill = (int*)((uint8_t*)d_ws + (16 * 32768) * sizeof(float2));

    prepass_kernel<false><<<dim3(8, 16, 32), 256, 0, stream>>>(x, xt, part, nullptr, colkill);
    gram_kernel<<<dim3(1152), 256, 0, stream>>>(xt, part, colkill);
    apply_kernel<<<65536, 256, 0, stream>>>(x, colkill, out);
  }
}